// Round 7
// baseline (207.760 us; speedup 1.0000x reference)
//
#include <hip/hip_runtime.h>
#include <stdint.h>

#pragma clang fp contract(off)

#define NCELL 49
#define NCLS  20
#define NSEG  16

struct Box { float x1, y1, x2, y2; };

// Bit-exact branchless sigmoid (see R9 note).
__device__ __forceinline__ float sigmoid_ref(float x) {
#pragma clang fp contract(off)
  float z = expf(-fabsf(x));
  float num = (x >= 0.0f) ? 1.0f : z;
  return num / (1.0f + z);
}

// Exact IoU (IEEE divide) — value feeds reference-visible comparisons.
__device__ __forceinline__ float iou_box(Box a, Box b) {
#pragma clang fp contract(off)
  float lx = fmaxf(a.x1, b.x1);
  float ly = fmaxf(a.y1, b.y1);
  float rx = fminf(a.x2, b.x2);
  float ry = fminf(a.y2, b.y2);
  float w = fmaxf(rx - lx, 0.0f);
  float h = fmaxf(ry - ly, 0.0f);
  float inter = w * h;
  float aa = (a.x2 - a.x1) * (a.y2 - a.y1);
  float ab = (b.x2 - b.x1) * (b.y2 - b.y1);
  return inter / (aa + ab - inter);
}

// (iou > 0.5) without the divide (R11; ~3e-8 one-sided window). Symmetric.
__device__ __forceinline__ bool iou_gt_half(Box a, Box b) {
#pragma clang fp contract(off)
  float lx = fmaxf(a.x1, b.x1);
  float ly = fmaxf(a.y1, b.y1);
  float rx = fminf(a.x2, b.x2);
  float ry = fminf(a.y2, b.y2);
  float w = fmaxf(rx - lx, 0.0f);
  float h = fmaxf(ry - ly, 0.0f);
  float inter = w * h;
  float aa = (a.x2 - a.x1) * (a.y2 - a.y1);
  float ab = (b.x2 - b.x1) * (b.y2 - b.y1);
  float u = aa + ab - inter;
  return inter > 0.5f * u;
}

__device__ __forceinline__ unsigned mbcnt64(unsigned long long m) {
  return __builtin_amdgcn_mbcnt_hi((unsigned)(m >> 32),
         __builtin_amdgcn_mbcnt_lo((unsigned)m, 0u));
}
#define WSYNC() __builtin_amdgcn_wave_barrier()

__device__ __forceinline__ unsigned match_mask(unsigned w, unsigned wantx4) {
  unsigned y = (w & 0x3f3f3f3fu) ^ wantx4;
  return ~(y + 0x7f7f7f7fu) & 0x80808080u;
}

__device__ __forceinline__ uint4 load_tile(const uint8_t* entries, int e, int e1, int ne) {
  uint4 w4 = make_uint4(0, 0, 0, 0);
  if (e < e1) {
    int p = e << 4;
    if (p + 16 <= ne) {
      w4 = *(const uint4*)(entries + p);
    } else {
      unsigned ws[4] = {0, 0, 0, 0};
      for (int k = 0; k < ne - p; ++k)
        ws[k >> 2] |= ((unsigned)entries[p + k]) << (8 * (k & 3));
      w4.x = ws[0]; w4.y = ws[1]; w4.z = ws[2]; w4.w = ws[3];
    }
  }
  return w4;
}

// R17: single fused kernel. Blocks [0, nimgb): image role (R15 k1 body,
// 2 independent waves = 2 images, no block barriers during compute), then
// __syncthreads + device-scope release signal on `done`. Blocks
// [nimgb, nimgb+320): AP role — precompute ranges, spin (s_sleep +
// acquire) until done == nimgb, then single-pass AP scan: each of 128
// lanes owns a CONTIGUOUS run of <=8 tiles (ascending order preserved),
// per-lane totals -> shfl_up wave prefix -> cross-wave via LDS ->
// cross-segment via `totals`. Deadlock-safe: launch_bounds(128,5) =>
// >=10 blocks/CU => >=2560 resident slots >= nimgb+320 (host-guarded;
// else falls back to the R15/R16 two-kernel path).
// Math identical to R16 modulo double-sum regrouping (same-sign terms).
__global__ __launch_bounds__(128, 5) void k_fused(
    const float* __restrict__ target, const float* __restrict__ output,
    uint8_t* __restrict__ entries, unsigned* __restrict__ gtseg,
    unsigned* __restrict__ totals, unsigned* __restrict__ done,
    double* __restrict__ partials, unsigned* __restrict__ counter2,
    float* __restrict__ out, int batch, int segimg, int nimgb, int ne)
{
#pragma clang fp contract(off)
  __shared__ float4   pbox [2][64];
  __shared__ int2     pcc  [2][64];
  __shared__ float4   gboxC[2][64];
  __shared__ int      gorig[2][64];
  __shared__ float    ctab [2][64];
  __shared__ int      claim[2][64];
  __shared__ unsigned phist[2][NCLS];
  __shared__ unsigned long long awt[2];
  __shared__ double   awacc[2];
  __shared__ int      islast;
  __shared__ float    apf_s[NCLS];
  __shared__ unsigned ghas_s[NCLS];

  int tid = threadIdx.x;
  int lane = tid & 63;
  int wv = tid >> 6;
  int bid = blockIdx.x;

  if (bid < nimgb) {
    // ==================== image role (R15 k1 body) ====================
    int img = bid * 2 + wv;
    bool act = (img < batch);
    if (act) {
      bool a = (lane < NCELL);
      int seg = img / segimg;

      if (lane < NCLS) phist[wv][lane] = 0u;
      claim[wv][lane] = 64;

      float fjx = (float)(lane % 7), fiy = (float)(lane / 7);

      // hoisted global loads
      float ov[30], tv[30];
      if (a) {
        const float2* O2 = (const float2*)(output + (size_t)img * 1470 + lane * 30);
        const float2* T2 = (const float2*)(target + (size_t)img * 1470 + lane * 30);
#pragma unroll
        for (int i = 0; i < 15; ++i) { float2 o = O2[i]; ov[2*i] = o.x; ov[2*i+1] = o.y; }
#pragma unroll
        for (int i = 0; i < 15; ++i) { float2 t = T2[i]; tv[2*i] = t.x; tv[2*i+1] = t.y; }
      } else {
#pragma unroll
        for (int i = 0; i < 30; ++i) { ov[i] = 0.0f; tv[i] = 0.0f; }
      }

      // phase 1: prediction decode + rank
      {
        float myc = -1.0f; int myk = 0; float px1 = 0, py1 = 0, px2 = 0, py2 = 0;
        if (a) {
          float x4 = ov[4], x9 = ov[9];
          float xm = fmaxf(x4, x9);
          float xc = ov[10], xr = -3.0e38f; int kk = 0;
#pragma unroll
          for (int c = 1; c < NCLS; ++c) {
            float v = ov[10 + c];
            bool gt = v > xc;
            float nr = gt ? xc : fmaxf(xr, v);
            kk = gt ? c : kk;
            xc = gt ? v : xc;
            xr = nr;
          }
          bool slowK = (xc - xr) < fmaxf(1e-5f, 4e-6f * exp2f(xc * 1.44269504f));
          bool slowR = fabsf(x4 - x9) < fmaxf(1e-5f, 4e-6f * exp2f(xm * 1.44269504f));
          int resp = (x9 > x4) ? 1 : 0;
          myc = sigmoid_ref(xm);
          myk = kk;
          if (slowK || slowR) {          // rare: exact reference fallback
            float s0 = sigmoid_ref(x4);
            float s1 = sigmoid_ref(x9);
            myc = fmaxf(s0, s1);
            resp = (s1 > s0) ? 1 : 0;
            float obv = sigmoid_ref(ov[10]); myk = 0;
#pragma unroll
            for (int c = 1; c < NCLS; ++c) {
              float v = sigmoid_ref(ov[10 + c]);
              if (v > obv) { obv = v; myk = c; }
            }
          }
          float bx = resp ? ov[5] : ov[0];
          float by = resp ? ov[6] : ov[1];
          float bw = resp ? ov[7] : ov[2];
          float bh = resp ? ov[8] : ov[3];
          float x  = sigmoid_ref(bx);
          float y  = sigmoid_ref(by);
          float ww = sigmoid_ref(bw);
          float hh = sigmoid_ref(bh);
          float cx = (x + fjx) * 64.0f, cy = (y + fiy) * 64.0f;
          float W = ww * 448.0f, H = hh * 448.0f;
          px1 = cx - W * 0.5f; py1 = cy - H * 0.5f;
          px2 = cx + W * 0.5f; py2 = cy + H * 0.5f;
        }
        ctab[wv][lane] = myc;
        WSYNC();
        int r = 0;
#pragma unroll
        for (int j = 0; j < NCELL; ++j) {
          float cj = ctab[wv][j];
          r += (cj > myc) || (cj == myc && j < lane);
        }
        r = a ? r : lane;
        pbox[wv][r] = make_float4(px1, py1, px2, py2);
        pcc [wv][r] = make_int2(myk, __float_as_int(myc));
      }

      // phase 2: GT decode + class-grouped stable compaction
      int mystartR = 0, myendR = 0;
      unsigned gcnt_mine = 0;
      int gclsv = 0; bool gval = false;
      float4 gb4;
      {
        float tbv = tv[10];
#pragma unroll
        for (int c = 1; c < NCLS; ++c) { float v = tv[10 + c]; if (v > tbv) { tbv = v; gclsv = c; } }
        gval = a && (tv[4] > 0.5f);
        float cx = (tv[0] + fjx) * 64.0f, cy = (tv[1] + fiy) * 64.0f;
        float w2 = tv[2] * 448.0f, h2 = tv[3] * 448.0f;
        gb4 = make_float4(cx - w2 * 0.5f, cy - h2 * 0.5f,
                          cx + w2 * 0.5f, cy + h2 * 0.5f);
      }

      WSYNC();
      float4 sb4 = pbox[wv][lane];
      int2 cc = pcc[wv][lane];
      Box myS; myS.x1 = sb4.x; myS.y1 = sb4.y; myS.x2 = sb4.z; myS.y2 = sb4.w;
      int scls = cc.x; float sconf = __int_as_float(cc.y);

      {
        int base = 0, mypos = -1;
#pragma unroll
        for (int c = 0; c < NCLS; ++c) {
          unsigned long long mc = __ballot(gval && (gclsv == c));
          int cnt = (int)__popcll(mc);
          if (scls == c) { mystartR = base; myendR = base + cnt; }
          if (gval && gclsv == c) mypos = base + (int)mbcnt64(mc);
          if (lane == c) gcnt_mine = (unsigned)cnt;
          base += cnt;
        }
        if (mypos >= 0) {
          gboxC[wv][mypos] = gb4;
          gorig[wv][mypos] = lane;
        }
        if (lane < NCLS && gcnt_mine) atomicAdd(&gtseg[seg * 32 + lane], gcnt_mine);
      }
      if (!a) { mystartR = 0; myendR = 0; }
      WSYNC();

      // phase 3: GT match (own-class segment only)
      float mx = -1.0f; int best = 0;
      for (int g = mystartR; g < myendR; ++g) {
        float4 b4 = gboxC[wv][g];
        int og = gorig[wv][g];
        Box bg; bg.x1 = b4.x; bg.y1 = b4.y; bg.x2 = b4.z; bg.y2 = b4.w;
        float v = iou_box(myS, bg);
        bool upd = (v > mx);
        mx = upd ? v : mx;
        best = upd ? og : best;
      }

      // phase 4: triangle cand build + sparse resolve
      unsigned long long row = 0;
#pragma unroll 4
      for (int t = 1; t <= 24; ++t) {
        int jr2 = lane + t;
        bool wrapped = (jr2 >= 49);
        int j = wrapped ? jr2 - 49 : jr2;
        float4 b4 = pbox[wv][j];
        int kj = pcc[wv][j].x;
        Box bj; bj.x1 = b4.x; bj.y1 = b4.y; bj.x2 = b4.z; bj.y2 = b4.w;
        bool s = a && (scls == kj) && iou_gt_half(myS, bj);
        row |= (s && !wrapped) ? (1ull << (jr2 & 63)) : 0ull;
        unsigned long long m2 = __ballot(s && wrapped);
        int idx = lane + 49 - t;
        unsigned long long bit = (m2 >> (idx & 63)) & 1ull;
        row |= (idx < 49) ? (bit << (idx & 63)) : 0ull;
      }
      unsigned long long anyrow = __ballot(row != 0ull);
      unsigned supbit = 0u;
      while (anyrow) {
        int i = (int)__builtin_ctzll(anyrow);
        anyrow &= anyrow - 1;
        unsigned long long ri = __shfl(row, i, 64);
        unsigned si = __shfl(supbit, i, 64);
        supbit |= (!si && ((ri >> lane) & 1ull)) ? 1u : 0u;
      }
      bool vp = a && (supbit == 0u) && (sconf > 0.5f);

      // phase 5: claim-table TP
      bool elig = vp && (mx > 0.5f);
      if (elig) atomicMin(&claim[wv][best], lane);
      WSYNC();
      bool hit = elig && (claim[wv][best] == lane);

      if (a) {
        entries[(size_t)img * NCELL + lane] =
            (uint8_t)(scls | (vp ? 32 : 0) | (hit ? 64 : 0));
      }

      // phase 6: stats
      unsigned add = (vp ? 0x10000u : 0u) | (hit ? 1u : 0u);
      if (a && add) atomicAdd(&phist[wv][scls], add);
      WSYNC();
      if (lane < NCLS) {
        unsigned pkt = phist[wv][lane];
        if (pkt) atomicAdd(&totals[seg * 32 + lane], pkt);
      }
    }
    // completion signal (canonical syncthreads+threadfence+atomic pattern)
    __syncthreads();
    if (tid == 0) {
      __threadfence();
      __hip_atomic_fetch_add(done, 1u, __ATOMIC_RELEASE, __HIP_MEMORY_SCOPE_AGENT);
    }
  } else {
    // ==================== AP role ====================
    int u = bid - nimgb;                 // = c*NSEG + s
    int c = u / NSEG, s = u % NSEG;
    unsigned wantx4 = (32u + (unsigned)c) * 0x01010101u;
    int nel = (ne + 15) >> 4;
    int segel = segimg * NCELL / 16;
    int se0 = s * segel; if (se0 > nel) se0 = nel;
    int se1 = se0 + segel; if (se1 > nel) se1 = nel;
    int navail = se1 - se0;
    int rl = (navail + 127) >> 7;        // tiles per lane, <=8 (host-guarded)
    int li = tid;                        // 0..127, contiguous ascending runs
    int myE0 = se0 + li * rl; if (myE0 > se1) myE0 = se1;
    int myE1 = myE0 + rl; if (myE1 > se1) myE1 = se1;

    // spin until all image blocks signal (acquire)
    if (tid == 0) {
      while (__hip_atomic_load(done, __ATOMIC_ACQUIRE, __HIP_MEMORY_SCOPE_AGENT)
             < (unsigned)nimgb)
        __builtin_amdgcn_s_sleep(16);
    }
    __syncthreads();

    unsigned gtc = 0;
#pragma unroll
    for (int s2 = 0; s2 < NSEG; ++s2) gtc += gtseg[s2 * 32 + c];
    float g2 = (float)gtc + 1e-6f;

    // stage this lane's tiles (static indexing; rl<=8)
    uint4 w4s[8];
#pragma unroll
    for (int t = 0; t < 8; ++t)
      w4s[t] = (t < rl) ? load_tile(entries, myE0 + t, myE1, ne)
                        : make_uint4(0, 0, 0, 0);

    // per-lane totals
    unsigned cv = 0, ct = 0;
#pragma unroll
    for (int t = 0; t < 8; ++t) {
      unsigned wsv[4] = {w4s[t].x, w4s[t].y, w4s[t].z, w4s[t].w};
#pragma unroll
      for (int q = 0; q < 4; ++q) {
        unsigned m = match_mask(wsv[q], wantx4);
        cv += __popc(m);
        ct += __popc(m & (wsv[q] << 1));
      }
    }

    // intra-wave inclusive prefix (packed; sums < 2^13, no cross-carry)
    unsigned long long pv = ((unsigned long long)cv << 32) | (unsigned long long)ct;
    unsigned long long scan = pv;
#pragma unroll
    for (int d = 1; d < 64; d <<= 1) {
      unsigned long long o = __shfl_up(scan, d, 64);
      if (lane >= d) scan += o;
    }
    unsigned long long wtot = __shfl(scan, 63, 64);
    if (lane == 0) awt[wv] = wtot;
    __syncthreads();
    unsigned long long excl = scan - pv;
    if (wv == 1) excl += awt[0];

    // cross-segment prefix from totals (exact ints)
    unsigned long long pk = 0;
    if (lane < s) {
      unsigned t2 = totals[lane * 32 + c];
      pk = ((unsigned long long)(t2 >> 16) << 32) | (unsigned long long)(t2 & 0xffffu);
    }
#pragma unroll
    for (int d = 1; d < 64; d <<= 1) pk += __shfl_xor(pk, d, 64);

    unsigned jr = (unsigned)(pk >> 32) + (unsigned)(excl >> 32);
    unsigned tr = (unsigned)(pk & 0xffffffffull) + (unsigned)(excl & 0xffffffffull);

    // walk own tiles in ascending order
    double acc = 0.0;
#pragma unroll
    for (int t = 0; t < 8; ++t) {
      if (t < rl && (myE0 + t) < myE1) {
        int p = (myE0 + t) << 4;
        unsigned wsv[4] = {w4s[t].x, w4s[t].y, w4s[t].z, w4s[t].w};
#pragma unroll
        for (int q = 0; q < 4; ++q) {
          unsigned m = match_mask(wsv[q], wantx4);
          unsigned tm = m & (wsv[q] << 1);
          while (m) {
            unsigned bit = (unsigned)__builtin_ctz(m);
            m &= m - 1;
            ++jr;
            if (tm & (1u << bit)) {
              ++tr;
              int pos = p + 4 * q + (int)(bit >> 3);
              float ft = (float)tr, fj = (float)jr;
              float r_cur  = ft / g2;
              float r_prev = (ft - 1.0f) / g2;
              float p_cur  = ft / (fj + 1e-6f);
              float p_prev = (pos == 0) ? 1.0f
                                        : (ft - 1.0f) / ((fj - 1.0f) + 1e-6f);
              acc += (double)((r_cur - r_prev) * (p_cur + p_prev) * 0.5f);
            }
          }
        }
      }
    }

    for (int d = 32; d > 0; d >>= 1) acc += __shfl_down(acc, d, 64);
    if (lane == 0) awacc[wv] = acc;
    __syncthreads();
    if (tid == 0) {
      double bp = awacc[0] + awacc[1];
      __hip_atomic_store(&partials[u], bp,
                         __ATOMIC_RELEASE, __HIP_MEMORY_SCOPE_AGENT);
      unsigned prev = __hip_atomic_fetch_add(counter2, 1u,
                         __ATOMIC_ACQ_REL, __HIP_MEMORY_SCOPE_AGENT);
      islast = (prev == (unsigned)(NCLS * NSEG - 1)) ? 1 : 0;
    }
    __syncthreads();
    if (islast) {
      if (tid < NCLS) {
        double d2 = 0.0;
#pragma unroll
        for (int s2 = 0; s2 < NSEG; ++s2)
          d2 += __hip_atomic_load(&partials[tid * NSEG + s2],
                                  __ATOMIC_ACQUIRE, __HIP_MEMORY_SCOPE_AGENT);
        apf_s[tid] = (float)d2;
        unsigned gc = 0;
#pragma unroll
        for (int s2 = 0; s2 < NSEG; ++s2) gc += gtseg[s2 * 32 + tid];
        ghas_s[tid] = gc;
      }
      __syncthreads();
      if (tid == 0) {
        float sf = 0.0f, nf = 0.0f;
        for (int cc2 = 0; cc2 < NCLS; ++cc2)
          if (ghas_s[cc2] > 0) { sf += apf_s[cc2]; nf += 1.0f; }
        out[0] = sf / fmaxf(nf, 1.0f);
      }
    }
  }
}

// ---------------- fallback path (R15/R16 two-kernel), host-guarded ----------------
__global__ __launch_bounds__(128) void k_per_image(
    const float* __restrict__ target, const float* __restrict__ output,
    uint8_t* __restrict__ entries, unsigned* __restrict__ gtseg,
    unsigned* __restrict__ totals, int batch, int segimg)
{
#pragma clang fp contract(off)
  __shared__ float4   pbox [2][64];
  __shared__ int2     pcc  [2][64];
  __shared__ float4   gboxC[2][64];
  __shared__ int      gorig[2][64];
  __shared__ float    ctab [2][64];
  __shared__ int      claim[2][64];
  __shared__ unsigned phist[2][NCLS];

  int tid = threadIdx.x;
  int lane = tid & 63;
  int wv = tid >> 6;
  int img = blockIdx.x * 2 + wv;
  if (img >= batch) return;
  bool a = (lane < NCELL);
  int seg = img / segimg;

  if (lane < NCLS) phist[wv][lane] = 0u;
  claim[wv][lane] = 64;

  float fjx = (float)(lane % 7), fiy = (float)(lane / 7);

  float ov[30], tv[30];
  if (a) {
    const float2* O2 = (const float2*)(output + (size_t)img * 1470 + lane * 30);
    const float2* T2 = (const float2*)(target + (size_t)img * 1470 + lane * 30);
#pragma unroll
    for (int i = 0; i < 15; ++i) { float2 o = O2[i]; ov[2*i] = o.x; ov[2*i+1] = o.y; }
#pragma unroll
    for (int i = 0; i < 15; ++i) { float2 t = T2[i]; tv[2*i] = t.x; tv[2*i+1] = t.y; }
  } else {
#pragma unroll
    for (int i = 0; i < 30; ++i) { ov[i] = 0.0f; tv[i] = 0.0f; }
  }

  {
    float myc = -1.0f; int myk = 0; float px1 = 0, py1 = 0, px2 = 0, py2 = 0;
    if (a) {
      float x4 = ov[4], x9 = ov[9];
      float xm = fmaxf(x4, x9);
      float xc = ov[10], xr = -3.0e38f; int kk = 0;
#pragma unroll
      for (int c = 1; c < NCLS; ++c) {
        float v = ov[10 + c];
        bool gt = v > xc;
        float nr = gt ? xc : fmaxf(xr, v);
        kk = gt ? c : kk;
        xc = gt ? v : xc;
        xr = nr;
      }
      bool slowK = (xc - xr) < fmaxf(1e-5f, 4e-6f * exp2f(xc * 1.44269504f));
      bool slowR = fabsf(x4 - x9) < fmaxf(1e-5f, 4e-6f * exp2f(xm * 1.44269504f));
      int resp = (x9 > x4) ? 1 : 0;
      myc = sigmoid_ref(xm);
      myk = kk;
      if (slowK || slowR) {
        float s0 = sigmoid_ref(x4);
        float s1 = sigmoid_ref(x9);
        myc = fmaxf(s0, s1);
        resp = (s1 > s0) ? 1 : 0;
        float obv = sigmoid_ref(ov[10]); myk = 0;
#pragma unroll
        for (int c = 1; c < NCLS; ++c) {
          float v = sigmoid_ref(ov[10 + c]);
          if (v > obv) { obv = v; myk = c; }
        }
      }
      float bx = resp ? ov[5] : ov[0];
      float by = resp ? ov[6] : ov[1];
      float bw = resp ? ov[7] : ov[2];
      float bh = resp ? ov[8] : ov[3];
      float x  = sigmoid_ref(bx);
      float y  = sigmoid_ref(by);
      float ww = sigmoid_ref(bw);
      float hh = sigmoid_ref(bh);
      float cx = (x + fjx) * 64.0f, cy = (y + fiy) * 64.0f;
      float W = ww * 448.0f, H = hh * 448.0f;
      px1 = cx - W * 0.5f; py1 = cy - H * 0.5f;
      px2 = cx + W * 0.5f; py2 = cy + H * 0.5f;
    }
    ctab[wv][lane] = myc;
    WSYNC();
    int r = 0;
#pragma unroll
    for (int j = 0; j < NCELL; ++j) {
      float cj = ctab[wv][j];
      r += (cj > myc) || (cj == myc && j < lane);
    }
    r = a ? r : lane;
    pbox[wv][r] = make_float4(px1, py1, px2, py2);
    pcc [wv][r] = make_int2(myk, __float_as_int(myc));
  }

  int mystartR = 0, myendR = 0;
  unsigned gcnt_mine = 0;
  int gclsv = 0; bool gval = false;
  float4 gb4;
  {
    float tbv = tv[10];
#pragma unroll
    for (int c = 1; c < NCLS; ++c) { float v = tv[10 + c]; if (v > tbv) { tbv = v; gclsv = c; } }
    gval = a && (tv[4] > 0.5f);
    float cx = (tv[0] + fjx) * 64.0f, cy = (tv[1] + fiy) * 64.0f;
    float w2 = tv[2] * 448.0f, h2 = tv[3] * 448.0f;
    gb4 = make_float4(cx - w2 * 0.5f, cy - h2 * 0.5f,
                      cx + w2 * 0.5f, cy + h2 * 0.5f);
  }

  WSYNC();
  float4 sb4 = pbox[wv][lane];
  int2 cc = pcc[wv][lane];
  Box myS; myS.x1 = sb4.x; myS.y1 = sb4.y; myS.x2 = sb4.z; myS.y2 = sb4.w;
  int scls = cc.x; float sconf = __int_as_float(cc.y);

  {
    int base = 0, mypos = -1;
#pragma unroll
    for (int c = 0; c < NCLS; ++c) {
      unsigned long long mc = __ballot(gval && (gclsv == c));
      int cnt = (int)__popcll(mc);
      if (scls == c) { mystartR = base; myendR = base + cnt; }
      if (gval && gclsv == c) mypos = base + (int)mbcnt64(mc);
      if (lane == c) gcnt_mine = (unsigned)cnt;
      base += cnt;
    }
    if (mypos >= 0) {
      gboxC[wv][mypos] = gb4;
      gorig[wv][mypos] = lane;
    }
    if (lane < NCLS && gcnt_mine) atomicAdd(&gtseg[seg * 32 + lane], gcnt_mine);
  }
  if (!a) { mystartR = 0; myendR = 0; }
  WSYNC();

  float mx = -1.0f; int best = 0;
  for (int g = mystartR; g < myendR; ++g) {
    float4 b4 = gboxC[wv][g];
    int og = gorig[wv][g];
    Box bg; bg.x1 = b4.x; bg.y1 = b4.y; bg.x2 = b4.z; bg.y2 = b4.w;
    float v = iou_box(myS, bg);
    bool upd = (v > mx);
    mx = upd ? v : mx;
    best = upd ? og : best;
  }

  unsigned long long row = 0;
#pragma unroll 4
  for (int t = 1; t <= 24; ++t) {
    int jr2 = lane + t;
    bool wrapped = (jr2 >= 49);
    int j = wrapped ? jr2 - 49 : jr2;
    float4 b4 = pbox[wv][j];
    int kj = pcc[wv][j].x;
    Box bj; bj.x1 = b4.x; bj.y1 = b4.y; bj.x2 = b4.z; bj.y2 = b4.w;
    bool s = a && (scls == kj) && iou_gt_half(myS, bj);
    row |= (s && !wrapped) ? (1ull << (jr2 & 63)) : 0ull;
    unsigned long long m2 = __ballot(s && wrapped);
    int idx = lane + 49 - t;
    unsigned long long bit = (m2 >> (idx & 63)) & 1ull;
    row |= (idx < 49) ? (bit << (idx & 63)) : 0ull;
  }
  unsigned long long anyrow = __ballot(row != 0ull);
  unsigned supbit = 0u;
  while (anyrow) {
    int i = (int)__builtin_ctzll(anyrow);
    anyrow &= anyrow - 1;
    unsigned long long ri = __shfl(row, i, 64);
    unsigned si = __shfl(supbit, i, 64);
    supbit |= (!si && ((ri >> lane) & 1ull)) ? 1u : 0u;
  }
  bool vp = a && (supbit == 0u) && (sconf > 0.5f);

  bool elig = vp && (mx > 0.5f);
  if (elig) atomicMin(&claim[wv][best], lane);
  WSYNC();
  bool hit = elig && (claim[wv][best] == lane);

  if (a) {
    entries[(size_t)img * NCELL + lane] =
        (uint8_t)(scls | (vp ? 32 : 0) | (hit ? 64 : 0));
  }

  unsigned add = (vp ? 0x10000u : 0u) | (hit ? 1u : 0u);
  if (a && add) atomicAdd(&phist[wv][scls], add);
  WSYNC();
  if (lane < NCLS) {
    unsigned pkt = phist[wv][lane];
    if (pkt) atomicAdd(&totals[seg * 32 + lane], pkt);
  }
}

__global__ __launch_bounds__(256) void k_apB(
    const uint8_t* __restrict__ entries, const unsigned* __restrict__ totals,
    const unsigned* __restrict__ gtseg, double* __restrict__ partials,
    unsigned* __restrict__ counter, float* __restrict__ out,
    int ne, int segimg)
{
#pragma clang fp contract(off)
  int c = blockIdx.x / NSEG, s = blockIdx.x % NSEG;
  int tid = threadIdx.x, wid = tid >> 6, lane = tid & 63;
  unsigned gtc = 0;
#pragma unroll
  for (int s2 = 0; s2 < NSEG; ++s2) gtc += gtseg[s2 * 32 + c];
  float g2 = (float)gtc + 1e-6f;
  unsigned wantx4 = (32u + (unsigned)c) * 0x01010101u;

  int nel = (ne + 15) >> 4;
  int segel = segimg * NCELL / 16;
  int se0 = s * segel; if (se0 > nel) se0 = nel;
  int se1 = se0 + segel; if (se1 > nel) se1 = nel;
  int elw = (se1 > se0) ? ((se1 - se0 + 3) >> 2) : 0;
  int e0 = se0 + wid * elw; if (e0 > se1) e0 = se1;
  int e1 = e0 + elw; if (e1 > se1) e1 = se1;
  int ntile = (e1 > e0) ? ((e1 - e0 + 63) >> 6) : 0;

  unsigned long long pk = 0;
  if (lane < s) {
    unsigned t2 = totals[lane * 32 + c];
    pk = ((unsigned long long)(t2 >> 16) << 32) | (unsigned long long)(t2 & 0xffffu);
  }
#pragma unroll
  for (int d = 1; d < 64; d <<= 1) pk += __shfl_xor(pk, d, 64);
  unsigned Jrun = (unsigned)(pk >> 32), Trun = (unsigned)(pk & 0xffffffffull);

  unsigned mv = 0, mt = 0;
  for (int t = 0; t < ntile; ++t) {
    uint4 w4 = load_tile(entries, e0 + t * 64 + lane, e1, ne);
    unsigned wsv[4] = {w4.x, w4.y, w4.z, w4.w};
#pragma unroll
    for (int q = 0; q < 4; ++q) {
      unsigned m = match_mask(wsv[q], wantx4);
      mv += __popc(m);
      mt += __popc(m & (wsv[q] << 1));
    }
  }
  unsigned long long tot = ((unsigned long long)mv << 32) | (unsigned long long)mt;
#pragma unroll
  for (int d = 1; d < 64; d <<= 1) tot += __shfl_xor(tot, d, 64);
  __shared__ unsigned long long wt[4];
  __shared__ double wacc[4];
  __shared__ int islast;
  __shared__ float apf_s[NCLS];
  __shared__ unsigned ghas_s[NCLS];
  if (lane == 0) wt[wid] = tot;
  __syncthreads();
  for (int w2 = 0; w2 < wid; ++w2) {
    Jrun += (unsigned)(wt[w2] >> 32);
    Trun += (unsigned)(wt[w2] & 0xffffffffull);
  }

  double acc = 0.0;
  for (int t = 0; t < ntile; ++t) {
    int e = e0 + t * 64 + lane;
    int p = e << 4;
    uint4 w4 = load_tile(entries, e, e1, ne);
    unsigned wsv[4] = {w4.x, w4.y, w4.z, w4.w};
    unsigned mm[4], tm[4];
    unsigned cv = 0, ct = 0;
#pragma unroll
    for (int q = 0; q < 4; ++q) {
      unsigned m = match_mask(wsv[q], wantx4);
      mm[q] = m; tm[q] = m & (wsv[q] << 1);
      cv += __popc(m); ct += __popc(tm[q]);
    }
    unsigned jexcl = 0, texcl = 0, jtt = 0, ttt = 0;
#pragma unroll
    for (int b = 0; b < 5; ++b) {
      unsigned long long mj = __ballot(((cv >> b) & 1u) != 0u);
      unsigned long long mk = __ballot(((ct >> b) & 1u) != 0u);
      jexcl += mbcnt64(mj) << b;
      texcl += mbcnt64(mk) << b;
      jtt   += (unsigned)__popcll(mj) << b;
      ttt   += (unsigned)__popcll(mk) << b;
    }
    unsigned jr = Jrun + jexcl;
    unsigned tr = Trun + texcl;
#pragma unroll
    for (int q = 0; q < 4; ++q) {
      unsigned m = mm[q];
      while (m) {
        unsigned bit = (unsigned)__builtin_ctz(m);
        m &= m - 1;
        ++jr;
        if (tm[q] & (1u << bit)) {
          ++tr;
          int pos = p + 4 * q + (int)(bit >> 3);
          float ft = (float)tr, fj = (float)jr;
          float r_cur  = ft / g2;
          float r_prev = (ft - 1.0f) / g2;
          float p_cur  = ft / (fj + 1e-6f);
          float p_prev = (pos == 0) ? 1.0f
                                    : (ft - 1.0f) / ((fj - 1.0f) + 1e-6f);
          acc += (double)((r_cur - r_prev) * (p_cur + p_prev) * 0.5f);
        }
      }
    }
    Jrun += jtt;
    Trun += ttt;
  }

  for (int d = 32; d > 0; d >>= 1) acc += __shfl_down(acc, d, 64);
  if (lane == 0) wacc[wid] = acc;
  __syncthreads();
  if (tid == 0) {
    double bp = wacc[0] + wacc[1] + wacc[2] + wacc[3];
    __hip_atomic_store(&partials[blockIdx.x], bp,
                       __ATOMIC_RELEASE, __HIP_MEMORY_SCOPE_AGENT);
    unsigned prev = __hip_atomic_fetch_add(counter, 1u,
                       __ATOMIC_ACQ_REL, __HIP_MEMORY_SCOPE_AGENT);
    islast = (prev == (unsigned)(NCLS * NSEG - 1)) ? 1 : 0;
  }
  __syncthreads();
  if (islast) {
    if (tid < NCLS) {
      double d2 = 0.0;
#pragma unroll
      for (int s2 = 0; s2 < NSEG; ++s2)
        d2 += __hip_atomic_load(&partials[tid * NSEG + s2],
                                __ATOMIC_ACQUIRE, __HIP_MEMORY_SCOPE_AGENT);
      apf_s[tid] = (float)d2;
      unsigned gc = 0;
#pragma unroll
      for (int s2 = 0; s2 < NSEG; ++s2) gc += gtseg[s2 * 32 + tid];
      ghas_s[tid] = gc;
    }
    __syncthreads();
    if (tid == 0) {
      float sf = 0.0f, nf = 0.0f;
      for (int cc = 0; cc < NCLS; ++cc)
        if (ghas_s[cc] > 0) { sf += apf_s[cc]; nf += 1.0f; }
      out[0] = sf / fmaxf(nf, 1.0f);
    }
  }
}

extern "C" void kernel_launch(void* const* d_in, const int* in_sizes, int n_in,
                              void* d_out, int out_size, void* d_ws, size_t ws_size,
                              hipStream_t stream) {
  const float* target = (const float*)d_in[0];
  const float* output = (const float*)d_in[1];
  int batch = in_sizes[0] / (NCELL * 30);
  int ne = batch * NCELL;
  int segimg = (((batch + NSEG - 1) / NSEG) + 15) & ~15;  // 16-image aligned

  uint8_t*  entries  = (uint8_t*)d_ws;
  size_t offA = ((size_t)ne + 255) & ~(size_t)255;
  unsigned* totals   = (unsigned*)((char*)d_ws + offA);            // 2048 B
  unsigned* gtseg    = (unsigned*)((char*)d_ws + offA + 2048);     // 2048 B
  unsigned* done     = (unsigned*)((char*)d_ws + offA + 4096);     // 4 B
  unsigned* counter2 = (unsigned*)((char*)d_ws + offA + 4100);     // 4 B
  double*   partials = (double*)((char*)d_ws + offA + 4608);       // 2560 B

  (void)hipMemsetAsync((char*)d_ws + offA, 0, 4608, stream);

  int nimgb = (batch + 1) / 2;
  int segel = segimg * NCELL / 16;
  int rl = (segel + 127) >> 7;
  // fused requires: per-lane tile run <=8 AND guaranteed full co-residency
  // (launch_bounds(128,5) => >=10 blocks/CU => 2560 slots)
  bool fused_ok = (rl <= 8) && (nimgb + NCLS * NSEG <= 2560);
  if (fused_ok) {
    k_fused<<<nimgb + NCLS * NSEG, 128, 0, stream>>>(
        target, output, entries, gtseg, totals, done, partials, counter2,
        (float*)d_out, batch, segimg, nimgb, ne);
  } else {
    k_per_image<<<nimgb, 128, 0, stream>>>(
        target, output, entries, gtseg, totals, batch, segimg);
    k_apB<<<NCLS * NSEG, 256, 0, stream>>>(
        entries, totals, gtseg, partials, counter2, (float*)d_out, ne, segimg);
  }
}

// Round 8
// 108.185 us; speedup vs baseline: 1.9204x; 1.9204x over previous
//
#include <hip/hip_runtime.h>
#include <stdint.h>

#pragma clang fp contract(off)

#define NCELL 49
#define NCLS  20
#define NSEG  16

struct Box { float x1, y1, x2, y2; };

// Bit-exact branchless sigmoid (see R9 note).
__device__ __forceinline__ float sigmoid_ref(float x) {
#pragma clang fp contract(off)
  float z = expf(-fabsf(x));
  float num = (x >= 0.0f) ? 1.0f : z;
  return num / (1.0f + z);
}

// Exact IoU (IEEE divide) — value feeds reference-visible comparisons.
__device__ __forceinline__ float iou_box(Box a, Box b) {
#pragma clang fp contract(off)
  float lx = fmaxf(a.x1, b.x1);
  float ly = fmaxf(a.y1, b.y1);
  float rx = fminf(a.x2, b.x2);
  float ry = fminf(a.y2, b.y2);
  float w = fmaxf(rx - lx, 0.0f);
  float h = fmaxf(ry - ly, 0.0f);
  float inter = w * h;
  float aa = (a.x2 - a.x1) * (a.y2 - a.y1);
  float ab = (b.x2 - b.x1) * (b.y2 - b.y1);
  return inter / (aa + ab - inter);
}

// (iou > 0.5) without the divide (R11; ~3e-8 one-sided window). Bit-symmetric
// in (a,b): max/min commute, inter identical, aa+ab commutative in IEEE.
__device__ __forceinline__ bool iou_gt_half(Box a, Box b) {
#pragma clang fp contract(off)
  float lx = fmaxf(a.x1, b.x1);
  float ly = fmaxf(a.y1, b.y1);
  float rx = fminf(a.x2, b.x2);
  float ry = fminf(a.y2, b.y2);
  float w = fmaxf(rx - lx, 0.0f);
  float h = fmaxf(ry - ly, 0.0f);
  float inter = w * h;
  float aa = (a.x2 - a.x1) * (a.y2 - a.y1);
  float ab = (b.x2 - b.x1) * (b.y2 - b.y1);
  float u = aa + ab - inter;
  return inter > 0.5f * u;
}

__device__ __forceinline__ unsigned mbcnt64(unsigned long long m) {
  return __builtin_amdgcn_mbcnt_hi((unsigned)(m >> 32),
         __builtin_amdgcn_mbcnt_lo((unsigned)m, 0u));
}
#define WSYNC() __builtin_amdgcn_wave_barrier()

// R18 = R15/R16 two-kernel structure (R17 fusion reverted: 2048 device-scope
// fences + 320 spin-pollers cost 110us of cache-maintenance traffic — a
// kernel boundary is cheaper). k1 change vs R15 (math identical, absmax 0.0):
//  * sparse same-class NMS build replaces the 24-iter triangle: pred-class
//    ballot masks are built inside the existing 20-iter GT-compaction loop
//    (+1 ballot/iter); each lane then walks only {j > lane, class==mine}
//    (~1.2 avg members vs 24 slots; wave cost = max class run ~5).
//    Candidate set identical: class equality encoded in the ballot,
//    iou_gt_half bit-symmetric => exact.                        [exact]
__global__ __launch_bounds__(128) void k_per_image(
    const float* __restrict__ target, const float* __restrict__ output,
    uint8_t* __restrict__ entries, unsigned* __restrict__ gtseg,
    unsigned* __restrict__ totals, int batch, int segimg)
{
#pragma clang fp contract(off)
  __shared__ float4   pbox [2][64];
  __shared__ int2     pcc  [2][64];
  __shared__ float4   gboxC[2][64];        // class-grouped valid GTs
  __shared__ int      gorig[2][64];        // original cell index g
  __shared__ float    ctab [2][64];
  __shared__ int      claim[2][64];        // first-claimant rank per GT
  __shared__ unsigned phist[2][NCLS];

  int tid = threadIdx.x;
  int lane = tid & 63;
  int wv = tid >> 6;
  int img = blockIdx.x * 2 + wv;
  if (img >= batch) return;        // wave-uniform; kernel has no block barriers
  bool a = (lane < NCELL);
  int seg = img / segimg;

  if (lane < NCLS) phist[wv][lane] = 0u;
  claim[wv][lane] = 64;

  float fjx = (float)(lane % 7), fiy = (float)(lane / 7);

  // ------- hoisted global loads: both tensors issued before any compute -------
  float ov[30], tv[30];
  if (a) {
    const float2* O2 = (const float2*)(output + (size_t)img * 1470 + lane * 30);
    const float2* T2 = (const float2*)(target + (size_t)img * 1470 + lane * 30);
#pragma unroll
    for (int i = 0; i < 15; ++i) { float2 o = O2[i]; ov[2*i] = o.x; ov[2*i+1] = o.y; }
#pragma unroll
    for (int i = 0; i < 15; ++i) { float2 t = T2[i]; tv[2*i] = t.x; tv[2*i+1] = t.y; }
  } else {
#pragma unroll
    for (int i = 0; i < 30; ++i) { ov[i] = 0.0f; tv[i] = 0.0f; }
  }

  // ---------------- phase 1: prediction decode + rank ----------------
  {
    float myc = -1.0f; int myk = 0; float px1 = 0, py1 = 0, px2 = 0, py2 = 0;
    if (a) {
      float x4 = ov[4], x9 = ov[9];
      float xm = fmaxf(x4, x9);
      // raw-domain class argmax with runner-up tracking
      float xc = ov[10], xr = -3.0e38f; int kk = 0;
#pragma unroll
      for (int c = 1; c < NCLS; ++c) {
        float v = ov[10 + c];
        bool gt = v > xc;
        float nr = gt ? xc : fmaxf(xr, v);
        kk = gt ? c : kk;
        xc = gt ? v : xc;
        xr = nr;
      }
      // conservative sigmoid-plateau slack: width <= ~2.4e-6*e^x
      bool slowK = (xc - xr) < fmaxf(1e-5f, 4e-6f * exp2f(xc * 1.44269504f));
      bool slowR = fabsf(x4 - x9) < fmaxf(1e-5f, 4e-6f * exp2f(xm * 1.44269504f));
      int resp = (x9 > x4) ? 1 : 0;
      myc = sigmoid_ref(xm);
      myk = kk;
      if (slowK || slowR) {          // rare: exact reference fallback
        float s0 = sigmoid_ref(x4);
        float s1 = sigmoid_ref(x9);
        myc = fmaxf(s0, s1);
        resp = (s1 > s0) ? 1 : 0;
        float obv = sigmoid_ref(ov[10]); myk = 0;
#pragma unroll
        for (int c = 1; c < NCLS; ++c) {
          float v = sigmoid_ref(ov[10 + c]);
          if (v > obv) { obv = v; myk = c; }
        }
      }
      float bx = resp ? ov[5] : ov[0];
      float by = resp ? ov[6] : ov[1];
      float bw = resp ? ov[7] : ov[2];
      float bh = resp ? ov[8] : ov[3];
      float x  = sigmoid_ref(bx);
      float y  = sigmoid_ref(by);
      float ww = sigmoid_ref(bw);
      float hh = sigmoid_ref(bh);
      float cx = (x + fjx) * 64.0f, cy = (y + fiy) * 64.0f;
      float W = ww * 448.0f, H = hh * 448.0f;
      px1 = cx - W * 0.5f; py1 = cy - H * 0.5f;
      px2 = cx + W * 0.5f; py2 = cy + H * 0.5f;
    }
    ctab[wv][lane] = myc;
    WSYNC();
    // stable rank (argsort(-conf), index tiebreak)
    int r = 0;
#pragma unroll
    for (int j = 0; j < NCELL; ++j) {
      float cj = ctab[wv][j];
      r += (cj > myc) || (cj == myc && j < lane);
    }
    r = a ? r : lane;
    pbox[wv][r] = make_float4(px1, py1, px2, py2);
    pcc [wv][r] = make_int2(myk, __float_as_int(myc));
  }

  // ------- phase 2: GT decode + fused class-ballot loop -------
  int mystartR = 0, myendR = 0;
  unsigned gcnt_mine = 0;
  int gclsv = 0; bool gval = false;
  float4 gb4;
  {
    float tbv = tv[10];
#pragma unroll
    for (int c = 1; c < NCLS; ++c) { float v = tv[10 + c]; if (v > tbv) { tbv = v; gclsv = c; } }
    gval = a && (tv[4] > 0.5f);
    float cx = (tv[0] + fjx) * 64.0f, cy = (tv[1] + fiy) * 64.0f;
    float w2 = tv[2] * 448.0f, h2 = tv[3] * 448.0f;
    gb4 = make_float4(cx - w2 * 0.5f, cy - h2 * 0.5f,
                      cx + w2 * 0.5f, cy + h2 * 0.5f);
  }

  // sorted self gathered after this wave's own phase-1 scatter (WSYNC orders)
  WSYNC();
  float4 sb4 = pbox[wv][lane];
  int2 cc = pcc[wv][lane];
  Box myS; myS.x1 = sb4.x; myS.y1 = sb4.y; myS.x2 = sb4.z; myS.y2 = sb4.w;
  int scls = cc.x; float sconf = __int_as_float(cc.y);

  unsigned long long mymask = 0;   // rank-bits of preds with my class
  {
    int base = 0, mypos = -1;
#pragma unroll
    for (int c = 0; c < NCLS; ++c) {
      unsigned long long mc = __ballot(gval && (gclsv == c));
      unsigned long long pc2 = __ballot(a && (scls == c));
      int cnt = (int)__popcll(mc);
      bool mine = (scls == c);
      if (mine) { mystartR = base; myendR = base + cnt; }
      mymask = mine ? pc2 : mymask;
      if (gval && gclsv == c) mypos = base + (int)mbcnt64(mc);
      if (lane == c) gcnt_mine = (unsigned)cnt;
      base += cnt;
    }
    if (mypos >= 0) {
      gboxC[wv][mypos] = gb4;
      gorig[wv][mypos] = lane;
    }
    // segment-sharded gt counts: 256 waves per address
    if (lane < NCLS && gcnt_mine) atomicAdd(&gtseg[seg * 32 + lane], gcnt_mine);
  }
  if (!a) { mystartR = 0; myendR = 0; }
  WSYNC();   // gboxC/gorig writes ordered before reads below

  // ---------------- phase 3: GT match (own-class segment only) ----------------
  float mx = -1.0f; int best = 0;
  for (int g = mystartR; g < myendR; ++g) {
    float4 b4 = gboxC[wv][g];
    int og = gorig[wv][g];
    Box bg; bg.x1 = b4.x; bg.y1 = b4.y; bg.x2 = b4.z; bg.y2 = b4.w;
    float v = iou_box(myS, bg);            // exact divide (value feeds v>mx)
    bool upd = (v > mx);
    mx = upd ? v : mx;
    best = upd ? og : best;
  }

  // ------- phase 4: sparse same-class cand build + sparse resolve -------
  // jm = same-class preds at HIGHER rank (lane+1 <= 49 for a-lanes: shift safe)
  unsigned long long jm = a ? ((mymask >> (lane + 1)) << (lane + 1)) : 0ull;
  unsigned long long row = 0;              // bits j that THIS rank suppresses
  while (jm) {
    int j = (int)__builtin_ctzll(jm);
    jm &= jm - 1;
    float4 b4 = pbox[wv][j];
    Box bj; bj.x1 = b4.x; bj.y1 = b4.y; bj.x2 = b4.z; bj.y2 = b4.w;
    row |= iou_gt_half(myS, bj) ? (1ull << j) : 0ull;
  }
  // sparse serial resolve: only rows with candidates, ascending
  unsigned long long anyrow = __ballot(row != 0ull);
  unsigned supbit = 0u;
  while (anyrow) {
    int i = (int)__builtin_ctzll(anyrow);
    anyrow &= anyrow - 1;
    unsigned long long ri = __shfl(row, i, 64);
    unsigned si = __shfl(supbit, i, 64);
    supbit |= (!si && ((ri >> lane) & 1ull)) ? 1u : 0u;
  }
  bool vp = a && (supbit == 0u) && (sconf > 0.5f);

  // ---------------- phase 5: claim-table TP (== serial greedy) ----------------
  bool elig = vp && (mx > 0.5f);
  if (elig) atomicMin(&claim[wv][best], lane);
  WSYNC();
  bool hit = elig && (claim[wv][best] == lane);

  if (a) {
    entries[(size_t)img * NCELL + lane] =
        (uint8_t)(scls | (vp ? 32 : 0) | (hit ? 64 : 0));
  }

  // ---------------- phase 6: stats ----------------
  unsigned add = (vp ? 0x10000u : 0u) | (hit ? 1u : 0u);
  if (a && add) atomicAdd(&phist[wv][scls], add);
  WSYNC();
  if (lane < NCLS) {
    unsigned pkt = phist[wv][lane];
    if (pkt) atomicAdd(&totals[seg * 32 + lane], pkt);
  }
}

__device__ __forceinline__ unsigned match_mask(unsigned w, unsigned wantx4) {
  unsigned y = (w & 0x3f3f3f3fu) ^ wantx4;
  return ~(y + 0x7f7f7f7fu) & 0x80808080u;
}

__device__ __forceinline__ uint4 load_tile(const uint8_t* entries, int e, int e1, int ne) {
  uint4 w4 = make_uint4(0, 0, 0, 0);
  if (e < e1) {
    int p = e << 4;
    if (p + 16 <= ne) {
      w4 = *(const uint4*)(entries + p);
    } else {
      unsigned ws[4] = {0, 0, 0, 0};
      for (int k = 0; k < ne - p; ++k)
        ws[k >> 2] |= ((unsigned)entries[p + k]) << (8 * (k & 3));
      w4.x = ws[0]; w4.y = ws[1]; w4.z = ws[2]; w4.w = ws[3];
    }
  }
  return w4;
}

// R16's 1024-thread single-pass apB (measured equal-best). Host-guarded
// rl<=8; fallback below for larger shapes.
__global__ __launch_bounds__(1024) void k_apB_fast(
    const uint8_t* __restrict__ entries, const unsigned* __restrict__ totals,
    const unsigned* __restrict__ gtseg, double* __restrict__ partials,
    unsigned* __restrict__ counter, float* __restrict__ out,
    int ne, int segimg)
{
#pragma clang fp contract(off)
  int c = blockIdx.x / NSEG, s = blockIdx.x % NSEG;
  int tid = threadIdx.x, wid = tid >> 6, lane = tid & 63;
  unsigned gtc = 0;
#pragma unroll
  for (int s2 = 0; s2 < NSEG; ++s2) gtc += gtseg[s2 * 32 + c];
  float g2 = (float)gtc + 1e-6f;
  unsigned wantx4 = (32u + (unsigned)c) * 0x01010101u;

  int nel = (ne + 15) >> 4;
  int segel = segimg * NCELL / 16;
  int se0 = s * segel; if (se0 > nel) se0 = nel;
  int se1 = se0 + segel; if (se1 > nel) se1 = nel;
  int elw = (se1 > se0) ? ((se1 - se0 + 15) >> 4) : 0;   // per-wave tiles, <=64
  int e0 = se0 + wid * elw; if (e0 > se1) e0 = se1;
  int e1 = e0 + elw; if (e1 > se1) e1 = se1;

  // global prefix from earlier segments (exact ints)
  unsigned long long pk = 0;
  if (lane < s) {
    unsigned t2 = totals[lane * 32 + c];
    pk = ((unsigned long long)(t2 >> 16) << 32) | (unsigned long long)(t2 & 0xffffu);
  }
#pragma unroll
  for (int d = 1; d < 64; d <<= 1) pk += __shfl_xor(pk, d, 64);
  unsigned Jrun = (unsigned)(pk >> 32), Trun = (unsigned)(pk & 0xffffffffull);

  // one tile per lane: load + match ONCE, masks live in registers
  int e = e0 + lane;
  int p = e << 4;
  uint4 w4 = load_tile(entries, e, e1, ne);
  unsigned wsv[4] = {w4.x, w4.y, w4.z, w4.w};
  unsigned mm[4], tm[4];
  unsigned cv = 0, ct = 0;
#pragma unroll
  for (int q = 0; q < 4; ++q) {
    unsigned m = match_mask(wsv[q], wantx4);
    mm[q] = m; tm[q] = m & (wsv[q] << 1);
    cv += __popc(m); ct += __popc(tm[q]);
  }

  // cross-wave prefix via LDS wave totals
  unsigned long long tot = ((unsigned long long)cv << 32) | (unsigned long long)ct;
#pragma unroll
  for (int d = 1; d < 64; d <<= 1) tot += __shfl_xor(tot, d, 64);
  __shared__ unsigned long long wt[16];
  __shared__ double wacc[16];
  __shared__ int islast;
  __shared__ float apf_s[NCLS];
  __shared__ unsigned ghas_s[NCLS];
  if (lane == 0) wt[wid] = tot;
  __syncthreads();
  for (int w2 = 0; w2 < wid; ++w2) {
    Jrun += (unsigned)(wt[w2] >> 32);
    Trun += (unsigned)(wt[w2] & 0xffffffffull);
  }

  // intra-wave exclusive prefix via 5-bit ballots (cv, ct <= 16)
  unsigned jexcl = 0, texcl = 0;
#pragma unroll
  for (int b = 0; b < 5; ++b) {
    unsigned long long mj = __ballot(((cv >> b) & 1u) != 0u);
    unsigned long long mk = __ballot(((ct >> b) & 1u) != 0u);
    jexcl += mbcnt64(mj) << b;
    texcl += mbcnt64(mk) << b;
  }
  unsigned jr = Jrun + jexcl;
  unsigned tr = Trun + texcl;

  double acc = 0.0;
#pragma unroll
  for (int q = 0; q < 4; ++q) {
    unsigned m = mm[q];
    while (m) {
      unsigned bit = (unsigned)__builtin_ctz(m);
      m &= m - 1;
      ++jr;
      if (tm[q] & (1u << bit)) {
        ++tr;
        int pos = p + 4 * q + (int)(bit >> 3);
        float ft = (float)tr, fj = (float)jr;
        float r_cur  = ft / g2;
        float r_prev = (ft - 1.0f) / g2;
        float p_cur  = ft / (fj + 1e-6f);
        float p_prev = (pos == 0) ? 1.0f
                                  : (ft - 1.0f) / ((fj - 1.0f) + 1e-6f);
        acc += (double)((r_cur - r_prev) * (p_cur + p_prev) * 0.5f);
      }
    }
  }

  for (int d = 32; d > 0; d >>= 1) acc += __shfl_down(acc, d, 64);
  if (lane == 0) wacc[wid] = acc;
  __syncthreads();
  if (tid == 0) {
    double bp = 0.0;
#pragma unroll
    for (int w2 = 0; w2 < 16; ++w2) bp += wacc[w2];
    __hip_atomic_store(&partials[blockIdx.x], bp,
                       __ATOMIC_RELEASE, __HIP_MEMORY_SCOPE_AGENT);
    unsigned prev = __hip_atomic_fetch_add(counter, 1u,
                       __ATOMIC_ACQ_REL, __HIP_MEMORY_SCOPE_AGENT);
    islast = (prev == (unsigned)(NCLS * NSEG - 1)) ? 1 : 0;
  }
  __syncthreads();
  if (islast) {
    if (tid < NCLS) {
      double d2 = 0.0;
#pragma unroll
      for (int s2 = 0; s2 < NSEG; ++s2)
        d2 += __hip_atomic_load(&partials[tid * NSEG + s2],
                                __ATOMIC_ACQUIRE, __HIP_MEMORY_SCOPE_AGENT);
      apf_s[tid] = (float)d2;
      unsigned gc = 0;
#pragma unroll
      for (int s2 = 0; s2 < NSEG; ++s2) gc += gtseg[s2 * 32 + tid];
      ghas_s[tid] = gc;
    }
    __syncthreads();
    if (tid == 0) {
      float sf = 0.0f, nf = 0.0f;
      for (int cc = 0; cc < NCLS; ++cc)
        if (ghas_s[cc] > 0) { sf += apf_s[cc]; nf += 1.0f; }
      out[0] = sf / fmaxf(nf, 1.0f);
    }
  }
}

// Fallback (two-pass, 256 thr) for segel > 1024 — never taken at batch 4096.
__global__ __launch_bounds__(256) void k_apB(
    const uint8_t* __restrict__ entries, const unsigned* __restrict__ totals,
    const unsigned* __restrict__ gtseg, double* __restrict__ partials,
    unsigned* __restrict__ counter, float* __restrict__ out,
    int ne, int segimg)
{
#pragma clang fp contract(off)
  int c = blockIdx.x / NSEG, s = blockIdx.x % NSEG;
  int tid = threadIdx.x, wid = tid >> 6, lane = tid & 63;
  unsigned gtc = 0;
#pragma unroll
  for (int s2 = 0; s2 < NSEG; ++s2) gtc += gtseg[s2 * 32 + c];
  float g2 = (float)gtc + 1e-6f;
  unsigned wantx4 = (32u + (unsigned)c) * 0x01010101u;

  int nel = (ne + 15) >> 4;
  int segel = segimg * NCELL / 16;
  int se0 = s * segel; if (se0 > nel) se0 = nel;
  int se1 = se0 + segel; if (se1 > nel) se1 = nel;
  int elw = (se1 > se0) ? ((se1 - se0 + 3) >> 2) : 0;
  int e0 = se0 + wid * elw; if (e0 > se1) e0 = se1;
  int e1 = e0 + elw; if (e1 > se1) e1 = se1;
  int ntile = (e1 > e0) ? ((e1 - e0 + 63) >> 6) : 0;

  unsigned long long pk = 0;
  if (lane < s) {
    unsigned t2 = totals[lane * 32 + c];
    pk = ((unsigned long long)(t2 >> 16) << 32) | (unsigned long long)(t2 & 0xffffu);
  }
#pragma unroll
  for (int d = 1; d < 64; d <<= 1) pk += __shfl_xor(pk, d, 64);
  unsigned Jrun = (unsigned)(pk >> 32), Trun = (unsigned)(pk & 0xffffffffull);

  unsigned mv = 0, mt = 0;
  for (int t = 0; t < ntile; ++t) {
    uint4 w4 = load_tile(entries, e0 + t * 64 + lane, e1, ne);
    unsigned wsv[4] = {w4.x, w4.y, w4.z, w4.w};
#pragma unroll
    for (int q = 0; q < 4; ++q) {
      unsigned m = match_mask(wsv[q], wantx4);
      mv += __popc(m);
      mt += __popc(m & (wsv[q] << 1));
    }
  }
  unsigned long long tot = ((unsigned long long)mv << 32) | (unsigned long long)mt;
#pragma unroll
  for (int d = 1; d < 64; d <<= 1) tot += __shfl_xor(tot, d, 64);
  __shared__ unsigned long long wt[4];
  __shared__ double wacc[4];
  __shared__ int islast;
  __shared__ float apf_s[NCLS];
  __shared__ unsigned ghas_s[NCLS];
  if (lane == 0) wt[wid] = tot;
  __syncthreads();
  for (int w2 = 0; w2 < wid; ++w2) {
    Jrun += (unsigned)(wt[w2] >> 32);
    Trun += (unsigned)(wt[w2] & 0xffffffffull);
  }

  double acc = 0.0;
  for (int t = 0; t < ntile; ++t) {
    int e = e0 + t * 64 + lane;
    int p = e << 4;
    uint4 w4 = load_tile(entries, e, e1, ne);
    unsigned wsv[4] = {w4.x, w4.y, w4.z, w4.w};
    unsigned mm[4], tm[4];
    unsigned cv = 0, ct = 0;
#pragma unroll
    for (int q = 0; q < 4; ++q) {
      unsigned m = match_mask(wsv[q], wantx4);
      mm[q] = m; tm[q] = m & (wsv[q] << 1);
      cv += __popc(m); ct += __popc(tm[q]);
    }
    unsigned jexcl = 0, texcl = 0, jtt = 0, ttt = 0;
#pragma unroll
    for (int b = 0; b < 5; ++b) {
      unsigned long long mj = __ballot(((cv >> b) & 1u) != 0u);
      unsigned long long mk = __ballot(((ct >> b) & 1u) != 0u);
      jexcl += mbcnt64(mj) << b;
      texcl += mbcnt64(mk) << b;
      jtt   += (unsigned)__popcll(mj) << b;
      ttt   += (unsigned)__popcll(mk) << b;
    }
    unsigned jr = Jrun + jexcl;
    unsigned tr = Trun + texcl;
#pragma unroll
    for (int q = 0; q < 4; ++q) {
      unsigned m = mm[q];
      while (m) {
        unsigned bit = (unsigned)__builtin_ctz(m);
        m &= m - 1;
        ++jr;
        if (tm[q] & (1u << bit)) {
          ++tr;
          int pos = p + 4 * q + (int)(bit >> 3);
          float ft = (float)tr, fj = (float)jr;
          float r_cur  = ft / g2;
          float r_prev = (ft - 1.0f) / g2;
          float p_cur  = ft / (fj + 1e-6f);
          float p_prev = (pos == 0) ? 1.0f
                                    : (ft - 1.0f) / ((fj - 1.0f) + 1e-6f);
          acc += (double)((r_cur - r_prev) * (p_cur + p_prev) * 0.5f);
        }
      }
    }
    Jrun += jtt;
    Trun += ttt;
  }

  for (int d = 32; d > 0; d >>= 1) acc += __shfl_down(acc, d, 64);
  if (lane == 0) wacc[wid] = acc;
  __syncthreads();
  if (tid == 0) {
    double bp = wacc[0] + wacc[1] + wacc[2] + wacc[3];
    __hip_atomic_store(&partials[blockIdx.x], bp,
                       __ATOMIC_RELEASE, __HIP_MEMORY_SCOPE_AGENT);
    unsigned prev = __hip_atomic_fetch_add(counter, 1u,
                       __ATOMIC_ACQ_REL, __HIP_MEMORY_SCOPE_AGENT);
    islast = (prev == (unsigned)(NCLS * NSEG - 1)) ? 1 : 0;
  }
  __syncthreads();
  if (islast) {
    if (tid < NCLS) {
      double d2 = 0.0;
#pragma unroll
      for (int s2 = 0; s2 < NSEG; ++s2)
        d2 += __hip_atomic_load(&partials[tid * NSEG + s2],
                                __ATOMIC_ACQUIRE, __HIP_MEMORY_SCOPE_AGENT);
      apf_s[tid] = (float)d2;
      unsigned gc = 0;
#pragma unroll
      for (int s2 = 0; s2 < NSEG; ++s2) gc += gtseg[s2 * 32 + tid];
      ghas_s[tid] = gc;
    }
    __syncthreads();
    if (tid == 0) {
      float sf = 0.0f, nf = 0.0f;
      for (int cc = 0; cc < NCLS; ++cc)
        if (ghas_s[cc] > 0) { sf += apf_s[cc]; nf += 1.0f; }
      out[0] = sf / fmaxf(nf, 1.0f);
    }
  }
}

extern "C" void kernel_launch(void* const* d_in, const int* in_sizes, int n_in,
                              void* d_out, int out_size, void* d_ws, size_t ws_size,
                              hipStream_t stream) {
  const float* target = (const float*)d_in[0];
  const float* output = (const float*)d_in[1];
  int batch = in_sizes[0] / (NCELL * 30);
  int ne = batch * NCELL;
  int segimg = (((batch + NSEG - 1) / NSEG) + 15) & ~15;  // 16-image aligned

  uint8_t*  entries  = (uint8_t*)d_ws;
  size_t offA = ((size_t)ne + 255) & ~(size_t)255;
  unsigned* totals   = (unsigned*)((char*)d_ws + offA);            // 2048 B
  unsigned* gtseg    = (unsigned*)((char*)d_ws + offA + 2048);     // 2048 B
  unsigned* counter  = (unsigned*)((char*)d_ws + offA + 4096);     // 4 B
  double*   partials = (double*)((char*)d_ws + offA + 4352);       // 2560 B

  (void)hipMemsetAsync((char*)d_ws + offA, 0, 4352, stream);
  k_per_image<<<(batch + 1) / 2, 128, 0, stream>>>(
      target, output, entries, gtseg, totals, batch, segimg);
  int segel = segimg * NCELL / 16;
  if (segel <= 1024) {
    k_apB_fast<<<NCLS * NSEG, 1024, 0, stream>>>(
        entries, totals, gtseg, partials, counter, (float*)d_out, ne, segimg);
  } else {
    k_apB<<<NCLS * NSEG, 256, 0, stream>>>(
        entries, totals, gtseg, partials, counter, (float*)d_out, ne, segimg);
  }
}